// Round 10
// baseline (442.961 us; speedup 1.0000x reference)
//
#include <hip/hip_runtime.h>
#include <hip/hip_bf16.h>
#include <hip/hip_fp8.h>

#define NR 8192
#define DIM 512   // fp8: bytes per row == elements

typedef __attribute__((ext_vector_type(2))) long  l64x2;
typedef __attribute__((ext_vector_type(4))) float f32x4;

__device__ static inline void gload_lds16(const void* g, void* l) {
    __builtin_amdgcn_global_load_lds(
        (const __attribute__((address_space(1))) void*)g,
        (__attribute__((address_space(3))) void*)l, 16, 0, 0);
}

// One block (256 threads) per row: |im|^2, |s|^2, im.s in one pass; write
// fp8(e4m3)-normalized rows in K-PERMUTED layout + exact fp32 diag.
// Permutation (within each 64-B K-window): orig k (j=k>>5 in {0,1},
// fc=(k>>3)&3, b=k&7) -> stored byte fc*16 + j*8 + b. MFMA lane group fc
// reads ONE 16-B slot {fc}: low 8 B = K-slice j0 operand, high 8 B = j1 —
// zero marshalling. Applied identically to A and B => dot products unchanged.
__global__ __launch_bounds__(256) void normalize_kernel(
    const float* __restrict__ im, const float* __restrict__ s,
    unsigned char* __restrict__ im_q, unsigned char* __restrict__ s_q,
    float* __restrict__ diag, double* __restrict__ acc,
    unsigned int* __restrict__ cnt)
{
    const int row = blockIdx.x;
    const int t = threadIdx.x;
    if (row == 0 && t == 0) { acc[0] = 0.0; cnt[0] = 0u; }

    const float2* imr = (const float2*)(im + (size_t)row * DIM);
    const float2* sr  = (const float2*)(s  + (size_t)row * DIM);
    float2 iv = imr[t];
    float2 sv = sr[t];

    float sim = iv.x * iv.x + iv.y * iv.y;
    float sss = sv.x * sv.x + sv.y * sv.y;
    float sd  = iv.x * sv.x + iv.y * sv.y;

    #pragma unroll
    for (int off = 32; off; off >>= 1) {
        sim += __shfl_down(sim, off);
        sss += __shfl_down(sss, off);
        sd  += __shfl_down(sd, off);
    }

    __shared__ float red[3][4];
    const int wid = t >> 6, lane = t & 63;
    if (lane == 0) { red[0][wid] = sim; red[1][wid] = sss; red[2][wid] = sd; }
    __syncthreads();
    sim = red[0][0] + red[0][1] + red[0][2] + red[0][3];
    sss = red[1][0] + red[1][1] + red[1][2] + red[1][3];
    sd  = red[2][0] + red[2][1] + red[2][2] + red[2][3];

    const float ri = rsqrtf(sim);
    const float rs = rsqrtf(sss);
    if (t == 0) diag[row] = sd * ri * rs;

    __hip_fp8_e4m3 qa0(iv.x * ri), qa1(iv.y * ri);
    __hip_fp8_e4m3 qb0(sv.x * rs), qb1(sv.y * rs);
    unsigned short ua = (unsigned short)qa0.__x | ((unsigned short)qa1.__x << 8);
    unsigned short ub = (unsigned short)qb0.__x | ((unsigned short)qb1.__x << 8);

    // permuted byte position for k0 = 2t (k0,k0+1 share j,fc; b even)
    const int k0 = 2 * t;
    const int win = k0 >> 6, inrow = k0 & 63;
    const int jj = (inrow >> 5) & 1, fcp = (inrow >> 3) & 3, bb = inrow & 7;
    const int np = win * 64 + fcp * 16 + jj * 8 + bb;
    *(unsigned short*)(im_q + (size_t)row * DIM + np) = ua;
    *(unsigned short*)(s_q  + (size_t)row * DIM + np) = ub;
}

// 256x256 tile, fp8, BK=64 (8 K-windows), 8 waves (2M x 4N). LDS = 64 KiB
// ([buf][256 rows][64 B] x A,B) -> TWO blocks/CU co-resident: one block's
// MFMA fills the other's barrier/vmcnt stalls (the ~60% lockstep exposure
// measured in R9's cycle audit). R9-verified 4-quadrant-phase schedule with
// the ledger halved: 1 gload/thread per half-tile, vmcnt(2) steady (each
// drain targets a half staged 2+ phases earlier; never 0 in main loop),
// tail 1 -> 0. Swizzle key (row>>1)&3: each 8-lane b128 service group hits
// all 32 banks (conflict-free, full width). Fragments typed long2 so the
// ds_read destination pair IS the MFMA operand (no repack VALU).
// Loss epilogue fused; finalize merged via device-scope completion counter.
__global__ __launch_bounds__(512, 4) void gemm_loss_kernel(
    const unsigned char* __restrict__ A,
    const unsigned char* __restrict__ B,
    const float* __restrict__ diag,
    double* __restrict__ acc_out,
    unsigned int* __restrict__ cnt,
    float* __restrict__ out)
{
    __shared__ char Asm[2][16384];   // [buf][256 rows][64 B]
    __shared__ char Bsm[2][16384];

    const int tid  = threadIdx.x;
    const int l    = tid & 63;
    const int w    = tid >> 6;          // wave 0..7
    const int wm   = w >> 2;            // 0..1
    const int wn   = w & 3;             // 0..3
    const int bm = blockIdx.y, bn = blockIdx.x;

    const int srow = l >> 2;            // staging: row within 16-row stripe
    const int sslot = l & 3;            // staging: 16B slot
    const int csw = sslot ^ ((l >> 3) & 3);  // slot ^ key(row), key=(row>>1)&3

    const int frow = l & 15;            // fragment lane row (output row/col)
    const int fc   = l >> 4;            // 0..3 k-group

    const char* Agb = (const char*)A + (size_t)bm * 256 * DIM;
    const char* Bgb = (const char*)B + (size_t)bn * 256 * DIM;

    // stage one half-tile (128 rows x 64 B): 1 gload/thread, wave-uniform dest
    auto stageA = [&](int b, int h, int tt) {
        const int row = h * 128 + w * 16 + srow;
        gload_lds16(Agb + (size_t)row * DIM + tt * 64 + csw * 16,
                    &Asm[b][h * 8192 + w * 1024]);
    };
    auto stageB = [&](int b, int h, int tt) {
        const int row = h * 128 + w * 16 + srow;
        gload_lds16(Bgb + (size_t)row * DIM + tt * 64 + csw * 16,
                    &Bsm[b][h * 8192 + w * 1024]);
    };

    // fragment reads: lane group fc reads slot fc^key(row) of its 16 rows;
    // long2 elements [0]/[1] are the j0/j1 MFMA operands directly.
    auto ldA = [&](l64x2 (&aF)[4], int b, int qm) {
        #pragma unroll
        for (int mi = 0; mi < 4; ++mi) {
            const int row = qm * 128 + wm * 64 + mi * 16 + frow;
            const int slot = fc ^ ((row >> 1) & 3);
            aF[mi] = *(const l64x2*)&Asm[b][row * 64 + slot * 16];
        }
    };
    auto ldB = [&](l64x2 (&bF)[2], int b, int qn) {
        #pragma unroll
        for (int ni = 0; ni < 2; ++ni) {
            const int row = qn * 128 + wn * 32 + ni * 16 + frow;
            const int slot = fc ^ ((row >> 1) & 3);
            bF[ni] = *(const l64x2*)&Bsm[b][row * 64 + slot * 16];
        }
    };

    f32x4 acc00[4][2], acc01[4][2], acc11[4][2], acc10[4][2];
    f32x4 zero = {0.f, 0.f, 0.f, 0.f};
    #pragma unroll
    for (int mi = 0; mi < 4; ++mi)
        #pragma unroll
        for (int ni = 0; ni < 2; ++ni) {
            acc00[mi][ni] = zero; acc01[mi][ni] = zero;
            acc11[mi][ni] = zero; acc10[mi][ni] = zero;
        }

    // one quadrant x K=64: 2 j-slices x (4m x 2n) = 16 MFMAs
    auto mmaq = [&](f32x4 (&ac)[4][2], l64x2 (&aF)[4], l64x2 (&bF)[2]) {
        __builtin_amdgcn_s_setprio(1);
        #pragma unroll
        for (int j = 0; j < 2; ++j)
            #pragma unroll
            for (int mi = 0; mi < 4; ++mi)
                #pragma unroll
                for (int ni = 0; ni < 2; ++ni)
                    ac[mi][ni] = __builtin_amdgcn_mfma_f32_16x16x32_fp8_fp8(
                        aF[mi][j], bF[ni][j], ac[mi][ni], 0, 0, 0);
        __builtin_amdgcn_s_setprio(0);
    };

    #define BAR __builtin_amdgcn_s_barrier()
    #define LGKM0_FENCE do { \
        asm volatile("s_waitcnt lgkmcnt(0)" ::: "memory"); \
        __builtin_amdgcn_sched_barrier(0); } while (0)

    l64x2 aF[4];     // current A-half frags (A0 in p1-p2, A1 in p3-p4)
    l64x2 bF0[2];    // B-half0, held p1 -> p4
    l64x2 bFB[2];    // B-half1

    // ---- prologue: stage K-window 0 (A0,B0,B1,A1); drain A0,B0 ----
    stageA(0, 0, 0); stageB(0, 0, 0); stageB(0, 1, 0); stageA(0, 1, 0);
    asm volatile("s_waitcnt vmcnt(2)" ::: "memory");
    BAR;

    // ---- main loop: windows t=0..6, staging window t+1 into buf^1 ----
    for (int t = 0; t < 7; ++t) {
        const int b = t & 1, nb = b ^ 1;

        // P1: quadrant (0,0) — 6 ds_reads, stage A0(t+1)
        ldA(aF, b, 0);
        ldB(bF0, b, 0);
        stageA(nb, 0, t + 1);
        asm volatile("s_waitcnt vmcnt(2)" ::: "memory");   // drains B1(t)
        BAR;
        LGKM0_FENCE;
        mmaq(acc00, aF, bF0);

        // P2: quadrant (0,1) — 2 ds_reads, stage B0(t+1)
        ldB(bFB, b, 1);
        stageB(nb, 0, t + 1);
        asm volatile("s_waitcnt vmcnt(2)" ::: "memory");   // drains A1(t)
        BAR;
        LGKM0_FENCE;
        mmaq(acc01, aF, bFB);

        // P3: quadrant (1,1) — 4 ds_reads, stage B1(t+1)
        ldA(aF, b, 1);
        stageB(nb, 1, t + 1);
        asm volatile("s_waitcnt vmcnt(2)" ::: "memory");   // drains A0(t+1)
        BAR;
        LGKM0_FENCE;
        mmaq(acc11, aF, bFB);

        // P4: quadrant (1,0) — 0 ds_reads (B0 held), stage A1(t+1)
        stageA(nb, 1, t + 1);
        asm volatile("s_waitcnt vmcnt(2)" ::: "memory");   // drains B0(t+1)
        BAR;
        __builtin_amdgcn_sched_barrier(0);
        mmaq(acc10, aF, bF0);
    }

    // ---- tail: window 7 in buf 1, no staging; drain 1 -> 0 ----
    {
        ldA(aF, 1, 0);
        ldB(bF0, 1, 0);
        asm volatile("s_waitcnt vmcnt(1)" ::: "memory");   // drains B1(7)
        BAR;
        LGKM0_FENCE;
        mmaq(acc00, aF, bF0);

        ldB(bFB, 1, 1);
        asm volatile("s_waitcnt vmcnt(0)" ::: "memory");   // drains A1(7)
        BAR;
        LGKM0_FENCE;
        mmaq(acc01, aF, bFB);

        ldA(aF, 1, 1);
        LGKM0_FENCE;
        mmaq(acc11, aF, bFB);
        mmaq(acc10, aF, bF0);
    }

    // ---- fused epilogue: relu(1 - diag[col] + sc) + relu(1 - diag[row] + sc)
    // C/D 16x16: col = lane&15 (=frow), row = (lane>>4)*4 + reg (fc*4+r)
    float lsum = 0.f;
    const int rb0 = bm * 256 + wm * 64;
    const int cb0 = bn * 256 + wn * 32;
    auto sumq = [&](f32x4 (&ac)[4][2], int qm, int qn) {
        #pragma unroll
        for (int mi = 0; mi < 4; ++mi) {
            const int rowb = rb0 + qm * 128 + mi * 16 + fc * 4;
            float dr[4];
            #pragma unroll
            for (int r = 0; r < 4; ++r) dr[r] = diag[rowb + r];
            #pragma unroll
            for (int ni = 0; ni < 2; ++ni) {
                const int col = cb0 + qn * 128 + ni * 16 + frow;
                const float dc = diag[col];
                #pragma unroll
                for (int r = 0; r < 4; ++r) {
                    if (rowb + r != col) {
                        const float sc = ac[mi][ni][r];
                        lsum += fmaxf(0.f, 1.0f - dc + sc)
                              + fmaxf(0.f, 1.0f - dr[r] + sc);
                    }
                }
            }
        }
    };
    sumq(acc00, 0, 0); sumq(acc01, 0, 1); sumq(acc11, 1, 1); sumq(acc10, 1, 0);

    #pragma unroll
    for (int off = 32; off; off >>= 1) lsum += __shfl_down(lsum, off);

    float* part = (float*)&Asm[0][0];   // reuse LDS (all tile reads done)
    __syncthreads();
    if (l == 0) part[w] = lsum;
    __syncthreads();
    if (tid == 0) {
        float bs = 0.f;
        #pragma unroll
        for (int i = 0; i < 8; ++i) bs += part[i];
        atomicAdd(acc_out, (double)bs);
        __threadfence();
        unsigned int old = atomicAdd(cnt, 1u);
        if (old == 1023u) {   // last of 1024 blocks: all adds visible
            double v = atomicAdd(acc_out, 0.0);   // device-scope read
            out[0] = (float)(v * (1.0 / (double)NR));
        }
    }
}

extern "C" void kernel_launch(void* const* d_in, const int* in_sizes, int n_in,
                              void* d_out, int out_size, void* d_ws, size_t ws_size,
                              hipStream_t stream)
{
    const float* im = (const float*)d_in[0];
    const float* s  = (const float*)d_in[1];

    char* ws = (char*)d_ws;
    unsigned char* im_q = (unsigned char*)ws;                                 // 4 MB
    unsigned char* s_q  = (unsigned char*)(ws + (size_t)NR * DIM);            // 4 MB
    float* diag         = (float*)(ws + (size_t)NR * DIM * 2);                // 32 KB
    double* acc         = (double*)(ws + (size_t)NR * DIM * 2 + NR * 4);      // 8 B
    unsigned int* cnt   = (unsigned int*)(ws + (size_t)NR * DIM * 2 + NR * 4 + 8);

    normalize_kernel<<<NR, 256, 0, stream>>>(im, s, im_q, s_q, diag, acc, cnt);

    dim3 grid(NR / 256, NR / 256);
    gemm_loss_kernel<<<grid, 512, 0, stream>>>(im_q, s_q, diag, acc, cnt,
                                               (float*)d_out);
}

// Round 11
// 92.689 us; speedup vs baseline: 4.7790x; 4.7790x over previous
//
#include <hip/hip_runtime.h>
#include <hip/hip_bf16.h>
#include <hip/hip_fp8.h>

#define NR 8192
#define DIM 512   // bytes per row in fp8 == elements

typedef __attribute__((ext_vector_type(2))) int   i32x2;
typedef __attribute__((ext_vector_type(4))) int   i32x4;
typedef __attribute__((ext_vector_type(4))) float f32x4;

__device__ static inline void gload_lds16(const void* g, void* l) {
    __builtin_amdgcn_global_load_lds(
        (const __attribute__((address_space(1))) void*)g,
        (__attribute__((address_space(3))) void*)l, 16, 0, 0);
}

__device__ static inline long pk64(int a, int b) {
    union { i32x2 v; long l; } u;
    u.v[0] = a; u.v[1] = b;
    return u.l;
}

// One block (256 threads) per row: |im|^2, |s|^2, im.s in one pass; write
// fp8(e4m3)-normalized rows in K-PERMUTED layout + exact fp32 diag.
// Permutation (within each 128-B K-window): orig k (j=k>>5, fc=(k>>3)&3,
// b=k&7) -> stored byte fc*16 + (j>>1)*64 + (j&1)*8 + b. MFMA lane group fc
// reads slot {fc} (j0,j1 operands) and slot {fc+4} (j2,j3) — R9's measured
// 0-conflict pattern. Applied identically to A and B => dots unchanged.
__global__ __launch_bounds__(256) void normalize_kernel(
    const float* __restrict__ im, const float* __restrict__ s,
    unsigned char* __restrict__ im_q, unsigned char* __restrict__ s_q,
    float* __restrict__ diag, double* __restrict__ acc,
    unsigned int* __restrict__ cnt)
{
    const int row = blockIdx.x;
    const int t = threadIdx.x;
    if (row == 0 && t == 0) { acc[0] = 0.0; cnt[0] = 0u; }

    const float2* imr = (const float2*)(im + (size_t)row * DIM);
    const float2* sr  = (const float2*)(s  + (size_t)row * DIM);
    float2 iv = imr[t];
    float2 sv = sr[t];

    float sim = iv.x * iv.x + iv.y * iv.y;
    float sss = sv.x * sv.x + sv.y * sv.y;
    float sd  = iv.x * sv.x + iv.y * sv.y;

    #pragma unroll
    for (int off = 32; off; off >>= 1) {
        sim += __shfl_down(sim, off);
        sss += __shfl_down(sss, off);
        sd  += __shfl_down(sd, off);
    }

    __shared__ float red[3][4];
    const int wid = t >> 6, lane = t & 63;
    if (lane == 0) { red[0][wid] = sim; red[1][wid] = sss; red[2][wid] = sd; }
    __syncthreads();
    sim = red[0][0] + red[0][1] + red[0][2] + red[0][3];
    sss = red[1][0] + red[1][1] + red[1][2] + red[1][3];
    sd  = red[2][0] + red[2][1] + red[2][2] + red[2][3];

    const float ri = rsqrtf(sim);
    const float rs = rsqrtf(sss);
    if (t == 0) diag[row] = sd * ri * rs;

    __hip_fp8_e4m3 qa0(iv.x * ri), qa1(iv.y * ri);
    __hip_fp8_e4m3 qb0(sv.x * rs), qb1(sv.y * rs);
    unsigned short ua = (unsigned short)qa0.__x | ((unsigned short)qa1.__x << 8);
    unsigned short ub = (unsigned short)qb0.__x | ((unsigned short)qb1.__x << 8);

    // permuted byte position for k0 = 2t (k0,k0+1 share j,fc; b even)
    const int k0 = 2 * t;
    const int win = k0 >> 7, inrow = k0 & 127;
    const int jj = (inrow >> 5) & 3, fcp = (inrow >> 3) & 3, bb = inrow & 7;
    const int np = win * 128 + fcp * 16 + (jj >> 1) * 64 + (jj & 1) * 8 + bb;
    *(unsigned short*)(im_q + (size_t)row * DIM + np) = ua;
    *(unsigned short*)(s_q  + (size_t)row * DIM + np) = ub;
}

// 256x256 tile, fp8, BK=128 (4 K-windows), 8 waves (2M x 4N), double-buffered
// LDS 128 KiB. R9's verified skeleton with phases merged 4 -> 2 per window
// (halves the lockstep sync boundaries, R9's dominant cost):
//  PA: {16 ds_reads (A0,B0,B1) || stage A0',B0' -> vmcnt(4) -> BAR -> lgkm0
//      -> 64 MFMA (q00,q01)}
//  PB: {8 ds_reads (A1) || stage B1',A1' -> vmcnt(2) -> BAR -> lgkm0
//      -> 64 MFMA (q11,q10)}
// Ledger: PB's vmcnt(2) leaves only A1' outstanding == exactly the halves
// PA(t+1) reads are already drained; PA's vmcnt(4) drains A1(t) before PB(t)
// reads it. Never 0 in the main loop. WAR on buffer re-stage crosses one
// full BAR whose arrival implies every wave lgkm-drained its reads.
__global__ __launch_bounds__(512, 2) void gemm_loss_kernel(
    const unsigned char* __restrict__ A,
    const unsigned char* __restrict__ B,
    const float* __restrict__ diag,
    double* __restrict__ acc_out,
    unsigned int* __restrict__ cnt,
    float* __restrict__ out)
{
    __shared__ char Asm[2][32768];   // [buf][256 rows][128 B]
    __shared__ char Bsm[2][32768];

    const int tid  = threadIdx.x;
    const int l    = tid & 63;
    const int w    = tid >> 6;          // wave 0..7
    const int wm   = w >> 2;            // 0..1
    const int wn   = w & 3;             // 0..3
    const int bm = blockIdx.y, bn = blockIdx.x;

    const int lr = l >> 3;              // 0..7 row within 8-row group
    const int ls = l & 7;               // 0..7 16B slot
    const int csw = ls ^ lr;            // swizzled content chunk for staging

    const int frow = l & 15;            // fragment lane row (output row/col)
    const int fc   = l >> 4;            // 0..3 k-group

    const char* Agb = (const char*)A + (size_t)bm * 256 * DIM;
    const char* Bgb = (const char*)B + (size_t)bn * 256 * DIM;

    auto stageA = [&](int b, int h, int tt) {
        #pragma unroll
        for (int q = 0; q < 2; ++q) {
            const int rit = h * 128 + q * 64 + w * 8 + lr;
            gload_lds16(Agb + (size_t)rit * DIM + tt * 128 + csw * 16,
                        &Asm[b][(h * 128 + q * 64 + w * 8) * 128]);
        }
    };
    auto stageB = [&](int b, int h, int tt) {
        #pragma unroll
        for (int q = 0; q < 2; ++q) {
            const int rit = h * 128 + q * 64 + w * 8 + lr;
            gload_lds16(Bgb + (size_t)rit * DIM + tt * 128 + csw * 16,
                        &Bsm[b][(h * 128 + q * 64 + w * 8) * 128]);
        }
    };

    // fragment reads: lane group fc reads slots {fc} and {fc+4}
    // (XOR-swizzled by row&7) of its 16 rows — R9's 0-conflict pattern.
    auto ldA = [&](i32x4 (&aL)[4], i32x4 (&aH)[4], int b, int qm) {
        #pragma unroll
        for (int mi = 0; mi < 4; ++mi) {
            const int row = qm * 128 + wm * 64 + mi * 16 + frow;
            const int rsw = (row & 7) << 4;
            aL[mi] = *(const i32x4*)&Asm[b][row * 128 + ((fc << 4) ^ rsw)];
            aH[mi] = *(const i32x4*)&Asm[b][row * 128 + (((fc + 4) << 4) ^ rsw)];
        }
    };
    auto ldB = [&](i32x4 (&bL)[2], i32x4 (&bH)[2], int b, int qn) {
        #pragma unroll
        for (int ni = 0; ni < 2; ++ni) {
            const int row = qn * 128 + wn * 32 + ni * 16 + frow;
            const int rsw = (row & 7) << 4;
            bL[ni] = *(const i32x4*)&Bsm[b][row * 128 + ((fc << 4) ^ rsw)];
            bH[ni] = *(const i32x4*)&Bsm[b][row * 128 + (((fc + 4) << 4) ^ rsw)];
        }
    };

    f32x4 acc00[4][2], acc01[4][2], acc11[4][2], acc10[4][2];
    f32x4 zero = {0.f, 0.f, 0.f, 0.f};
    #pragma unroll
    for (int mi = 0; mi < 4; ++mi)
        #pragma unroll
        for (int ni = 0; ni < 2; ++ni) {
            acc00[mi][ni] = zero; acc01[mi][ni] = zero;
            acc11[mi][ni] = zero; acc10[mi][ni] = zero;
        }

    // one quadrant x K=128: j-slices j0,j1 from lo regs, j2,j3 from hi regs
    auto mmaq = [&](f32x4 (&ac)[4][2], i32x4 (&aL)[4], i32x4 (&aH)[4],
                    i32x4 (&bL)[2], i32x4 (&bH)[2]) {
        __builtin_amdgcn_s_setprio(1);
        #pragma unroll
        for (int j = 0; j < 4; ++j) {
            long bv0 = (j < 2) ? pk64(bL[0][(j & 1) * 2], bL[0][(j & 1) * 2 + 1])
                               : pk64(bH[0][(j & 1) * 2], bH[0][(j & 1) * 2 + 1]);
            long bv1 = (j < 2) ? pk64(bL[1][(j & 1) * 2], bL[1][(j & 1) * 2 + 1])
                               : pk64(bH[1][(j & 1) * 2], bH[1][(j & 1) * 2 + 1]);
            #pragma unroll
            for (int mi = 0; mi < 4; ++mi) {
                long av = (j < 2) ? pk64(aL[mi][(j & 1) * 2], aL[mi][(j & 1) * 2 + 1])
                                  : pk64(aH[mi][(j & 1) * 2], aH[mi][(j & 1) * 2 + 1]);
                ac[mi][0] = __builtin_amdgcn_mfma_f32_16x16x32_fp8_fp8(
                    av, bv0, ac[mi][0], 0, 0, 0);
                ac[mi][1] = __builtin_amdgcn_mfma_f32_16x16x32_fp8_fp8(
                    av, bv1, ac[mi][1], 0, 0, 0);
            }
        }
        __builtin_amdgcn_s_setprio(0);
    };

    #define BAR __builtin_amdgcn_s_barrier()
    #define LGKM0_FENCE do { \
        asm volatile("s_waitcnt lgkmcnt(0)" ::: "memory"); \
        __builtin_amdgcn_sched_barrier(0); } while (0)

    i32x4 aL[4], aH[4];     // A-half frags (A0 in PA, A1 in PB)
    i32x4 b0L[2], b0H[2];   // B-half0, read PA, held through PB
    i32x4 bBL[2], bBH[2];   // B-half1, read PA, held through PB

    // ---- prologue: stage K-window 0 (A0,B0,B1,A1); drain A0,B0,B1 ----
    stageA(0, 0, 0); stageB(0, 0, 0); stageB(0, 1, 0); stageA(0, 1, 0);
    asm volatile("s_waitcnt vmcnt(2)" ::: "memory");
    BAR;

    // ---- main loop: windows t=0..2, staging window t+1 into buf^1 ----
    for (int t = 0; t < 3; ++t) {
        const int b = t & 1, nb = b ^ 1;

        // PA: 16 ds_reads (A0,B0,B1), stage A0',B0'
        ldA(aL, aH, b, 0);
        ldB(b0L, b0H, b, 0);
        ldB(bBL, bBH, b, 1);
        stageA(nb, 0, t + 1);
        stageB(nb, 0, t + 1);
        asm volatile("s_waitcnt vmcnt(4)" ::: "memory");   // drains A1(t)
        BAR;
        LGKM0_FENCE;
        mmaq(acc00, aL, aH, b0L, b0H);
        mmaq(acc01, aL, aH, bBL, bBH);

        // PB: 8 ds_reads (A1), stage B1',A1'
        ldA(aL, aH, b, 1);
        stageB(nb, 1, t + 1);
        stageA(nb, 1, t + 1);
        asm volatile("s_waitcnt vmcnt(2)" ::: "memory");   // drains A0',B0',B1'
        BAR;
        LGKM0_FENCE;
        mmaq(acc11, aL, aH, bBL, bBH);
        mmaq(acc10, aL, aH, b0L, b0H);
    }

    // ---- tail: window 3 in buf 1, no staging; drain A1(3) then compute ----
    {
        ldA(aL, aH, 1, 0);
        ldB(b0L, b0H, 1, 0);
        ldB(bBL, bBH, 1, 1);
        asm volatile("s_waitcnt vmcnt(0)" ::: "memory");   // drains A1(3)
        BAR;
        LGKM0_FENCE;
        mmaq(acc00, aL, aH, b0L, b0H);
        mmaq(acc01, aL, aH, bBL, bBH);

        ldA(aL, aH, 1, 1);
        LGKM0_FENCE;
        mmaq(acc11, aL, aH, bBL, bBH);
        mmaq(acc10, aL, aH, b0L, b0H);
    }

    // ---- fused epilogue: relu(1 - diag[col] + sc) + relu(1 - diag[row] + sc)
    // C/D 16x16: col = lane&15 (=frow), row = (lane>>4)*4 + reg (fc*4+r)
    float lsum = 0.f;
    const int rb0 = bm * 256 + wm * 64;
    const int cb0 = bn * 256 + wn * 32;
    auto sumq = [&](f32x4 (&ac)[4][2], int qm, int qn) {
        #pragma unroll
        for (int mi = 0; mi < 4; ++mi) {
            const int rowb = rb0 + qm * 128 + mi * 16 + fc * 4;
            float dr[4];
            #pragma unroll
            for (int r = 0; r < 4; ++r) dr[r] = diag[rowb + r];
            #pragma unroll
            for (int ni = 0; ni < 2; ++ni) {
                const int col = cb0 + qn * 128 + ni * 16 + frow;
                const float dc = diag[col];
                #pragma unroll
                for (int r = 0; r < 4; ++r) {
                    if (rowb + r != col) {
                        const float sc = ac[mi][ni][r];
                        lsum += fmaxf(0.f, 1.0f - dc + sc)
                              + fmaxf(0.f, 1.0f - dr[r] + sc);
                    }
                }
            }
        }
    };
    sumq(acc00, 0, 0); sumq(acc01, 0, 1); sumq(acc11, 1, 1); sumq(acc10, 1, 0);

    #pragma unroll
    for (int off = 32; off; off >>= 1) lsum += __shfl_down(lsum, off);

    float* part = (float*)&Asm[0][0];   // reuse LDS (all tile reads done)
    __syncthreads();
    if (l == 0) part[w] = lsum;
    __syncthreads();
    if (tid == 0) {
        float bs = 0.f;
        #pragma unroll
        for (int i = 0; i < 8; ++i) bs += part[i];
        atomicAdd(acc_out, (double)bs);
        __threadfence();
        unsigned int old = atomicAdd(cnt, 1u);
        if (old == 1023u) {   // last of 1024 blocks: all adds visible
            double v = atomicAdd(acc_out, 0.0);   // device-scope read
            out[0] = (float)(v * (1.0 / (double)NR));
        }
    }
}

extern "C" void kernel_launch(void* const* d_in, const int* in_sizes, int n_in,
                              void* d_out, int out_size, void* d_ws, size_t ws_size,
                              hipStream_t stream)
{
    const float* im = (const float*)d_in[0];
    const float* s  = (const float*)d_in[1];

    char* ws = (char*)d_ws;
    unsigned char* im_q = (unsigned char*)ws;                                 // 4 MB
    unsigned char* s_q  = (unsigned char*)(ws + (size_t)NR * DIM);            // 4 MB
    float* diag         = (float*)(ws + (size_t)NR * DIM * 2);                // 32 KB
    double* acc         = (double*)(ws + (size_t)NR * DIM * 2 + NR * 4);      // 8 B
    unsigned int* cnt   = (unsigned int*)(ws + (size_t)NR * DIM * 2 + NR * 4 + 8);

    normalize_kernel<<<NR, 256, 0, stream>>>(im, s, im_q, s_q, diag, acc, cnt);

    dim3 grid(NR / 256, NR / 256);
    gemm_loss_kernel<<<grid, 512, 0, stream>>>(im_q, s_q, diag, acc, cnt,
                                               (float*)d_out);
}

// Round 12
// 79.136 us; speedup vs baseline: 5.5974x; 1.1713x over previous
//
#include <hip/hip_runtime.h>
#include <hip/hip_bf16.h>
#include <hip/hip_fp8.h>

#define NR 8192
#define DIM 512   // bytes per row in fp8 == elements

typedef __attribute__((ext_vector_type(2))) long  l64x2;
typedef __attribute__((ext_vector_type(4))) float f32x4;

__device__ static inline void gload_lds16(const void* g, void* l) {
    __builtin_amdgcn_global_load_lds(
        (const __attribute__((address_space(1))) void*)g,
        (__attribute__((address_space(3))) void*)l, 16, 0, 0);
}

// One block (256 threads) per row: |im|^2, |s|^2, im.s in one pass; write
// fp8(e4m3)-normalized rows in K-PERMUTED layout + exact fp32 diag.
// Permutation (within each 128-B K-window): orig k (j=k>>5, fc=(k>>3)&3,
// b=k&7) -> stored byte fc*16 + (j>>1)*64 + (j&1)*8 + b. MFMA lane group fc
// reads slot {fc} (j0,j1 operands) and slot {fc+4} (j2,j3) — R9's measured
// 0-conflict pattern. Applied identically to A and B => dots unchanged.
__global__ __launch_bounds__(256) void normalize_kernel(
    const float* __restrict__ im, const float* __restrict__ s,
    unsigned char* __restrict__ im_q, unsigned char* __restrict__ s_q,
    float* __restrict__ diag, double* __restrict__ acc,
    unsigned int* __restrict__ cnt)
{
    const int row = blockIdx.x;
    const int t = threadIdx.x;
    if (row == 0 && t == 0) { acc[0] = 0.0; cnt[0] = 0u; }

    const float2* imr = (const float2*)(im + (size_t)row * DIM);
    const float2* sr  = (const float2*)(s  + (size_t)row * DIM);
    float2 iv = imr[t];
    float2 sv = sr[t];

    float sim = iv.x * iv.x + iv.y * iv.y;
    float sss = sv.x * sv.x + sv.y * sv.y;
    float sd  = iv.x * sv.x + iv.y * sv.y;

    #pragma unroll
    for (int off = 32; off; off >>= 1) {
        sim += __shfl_down(sim, off);
        sss += __shfl_down(sss, off);
        sd  += __shfl_down(sd, off);
    }

    __shared__ float red[3][4];
    const int wid = t >> 6, lane = t & 63;
    if (lane == 0) { red[0][wid] = sim; red[1][wid] = sss; red[2][wid] = sd; }
    __syncthreads();
    sim = red[0][0] + red[0][1] + red[0][2] + red[0][3];
    sss = red[1][0] + red[1][1] + red[1][2] + red[1][3];
    sd  = red[2][0] + red[2][1] + red[2][2] + red[2][3];

    const float ri = rsqrtf(sim);
    const float rs = rsqrtf(sss);
    if (t == 0) diag[row] = sd * ri * rs;

    __hip_fp8_e4m3 qa0(iv.x * ri), qa1(iv.y * ri);
    __hip_fp8_e4m3 qb0(sv.x * rs), qb1(sv.y * rs);
    unsigned short ua = (unsigned short)qa0.__x | ((unsigned short)qa1.__x << 8);
    unsigned short ub = (unsigned short)qb0.__x | ((unsigned short)qb1.__x << 8);

    // permuted byte position for k0 = 2t (k0,k0+1 share j,fc; b even)
    const int k0 = 2 * t;
    const int win = k0 >> 7, inrow = k0 & 127;
    const int jj = (inrow >> 5) & 3, fcp = (inrow >> 3) & 3, bb = inrow & 7;
    const int np = win * 128 + fcp * 16 + (jj >> 1) * 64 + (jj & 1) * 8 + bb;
    *(unsigned short*)(im_q + (size_t)row * DIM + np) = ua;
    *(unsigned short*)(s_q  + (size_t)row * DIM + np) = ub;
}

// Persistent GEMM: grid 256 (1 block/CU), block b owns 4 tiles in one row
// (bm = b>>3, bn = (b&7)*4 + j) -> A panel reused 4x, ONE pipeline fill and
// drain per CU (R9 paid 4). 16 continuous K-windows (BK=128), per-window
// schedule byte-identical to R9's verified 4-phase/1-barrier structure with
// its vmcnt(4) ledger (never 0 in the main loop). Fragments typed l64x2 so
// ds_read_b128 destination pairs feed MFMA directly (no pk64 movs — R9's
// VALU drag). diag cached in LDS: per-tile epilogues are register+LDS only
// (no vmem -> ledger untouched) and overlap the next tile's staging.
__global__ __launch_bounds__(512, 2) void gemm_loss_kernel(
    const unsigned char* __restrict__ A,
    const unsigned char* __restrict__ B,
    const float* __restrict__ diag,
    double* __restrict__ acc_out,
    unsigned int* __restrict__ cnt,
    float* __restrict__ out)
{
    __shared__ char Asm[2][32768];   // [buf][256 rows][128 B]
    __shared__ char Bsm[2][32768];
    __shared__ float dAr[256];       // diag rows  bm*256 ..
    __shared__ float dBc[1024];      // diag cols  (b&7)*1024 ..
    __shared__ float part[8];

    const int tid  = threadIdx.x;
    const int l    = tid & 63;
    const int w    = tid >> 6;          // wave 0..7
    const int wm   = w >> 2;            // 0..1
    const int wn   = w & 3;             // 0..3
    const int bm  = blockIdx.x >> 3;    // tile row 0..31
    const int bn0 = (blockIdx.x & 7) * 4;  // first tile col

    const int lr = l >> 3;              // 0..7 row within 8-row group
    const int ls = l & 7;               // 0..7 16B slot
    const int csw = ls ^ lr;            // swizzled content chunk for staging

    const int frow = l & 15;            // fragment lane row (output row/col)
    const int fc   = l >> 4;            // 0..3 k-group

    const char* Agb = (const char*)A + (size_t)bm * 256 * DIM;
    const char* Bgb = (const char*)B + (size_t)bn0 * 256 * DIM;

    // stage half-tiles of global window g2 (tile g2>>2, K-window g2&3)
    auto stageA = [&](int b, int h, int g2) {
        const int kk = g2 & 3;
        #pragma unroll
        for (int q = 0; q < 2; ++q) {
            const int rit = h * 128 + q * 64 + w * 8 + lr;
            gload_lds16(Agb + (size_t)rit * DIM + kk * 128 + csw * 16,
                        &Asm[b][(h * 128 + q * 64 + w * 8) * 128]);
        }
    };
    auto stageB = [&](int b, int h, int g2) {
        const int kk = g2 & 3;
        const char* Bt = Bgb + (size_t)(g2 >> 2) * 256 * DIM;
        #pragma unroll
        for (int q = 0; q < 2; ++q) {
            const int rit = h * 128 + q * 64 + w * 8 + lr;
            gload_lds16(Bt + (size_t)rit * DIM + kk * 128 + csw * 16,
                        &Bsm[b][(h * 128 + q * 64 + w * 8) * 128]);
        }
    };

    // fragment reads: lane group fc reads slots {fc} and {fc+4}
    // (XOR-swizzled by row&7) — R9's 0-conflict pattern. l64x2 elements
    // [0]/[1] of each slot are the j0/j1 (resp. j2/j3) MFMA operands.
    auto ldA = [&](l64x2 (&aL)[4], l64x2 (&aH)[4], int b, int qm) {
        #pragma unroll
        for (int mi = 0; mi < 4; ++mi) {
            const int row = qm * 128 + wm * 64 + mi * 16 + frow;
            const int rsw = (row & 7) << 4;
            aL[mi] = *(const l64x2*)&Asm[b][row * 128 + ((fc << 4) ^ rsw)];
            aH[mi] = *(const l64x2*)&Asm[b][row * 128 + (((fc + 4) << 4) ^ rsw)];
        }
    };
    auto ldB = [&](l64x2 (&bL)[2], l64x2 (&bH)[2], int b, int qn) {
        #pragma unroll
        for (int ni = 0; ni < 2; ++ni) {
            const int row = qn * 128 + wn * 32 + ni * 16 + frow;
            const int rsw = (row & 7) << 4;
            bL[ni] = *(const l64x2*)&Bsm[b][row * 128 + ((fc << 4) ^ rsw)];
            bH[ni] = *(const l64x2*)&Bsm[b][row * 128 + (((fc + 4) << 4) ^ rsw)];
        }
    };

    f32x4 acc00[4][2], acc01[4][2], acc11[4][2], acc10[4][2];
    f32x4 zero = {0.f, 0.f, 0.f, 0.f};
    #pragma unroll
    for (int mi = 0; mi < 4; ++mi)
        #pragma unroll
        for (int ni = 0; ni < 2; ++ni) {
            acc00[mi][ni] = zero; acc01[mi][ni] = zero;
            acc11[mi][ni] = zero; acc10[mi][ni] = zero;
        }

    // one quadrant x K=128: j0,j1 from lo slots, j2,j3 from hi slots
    auto mmaq = [&](f32x4 (&ac)[4][2], l64x2 (&aL)[4], l64x2 (&aH)[4],
                    l64x2 (&bL)[2], l64x2 (&bH)[2]) {
        __builtin_amdgcn_s_setprio(1);
        #pragma unroll
        for (int j = 0; j < 4; ++j) {
            const long bv0 = (j < 2) ? bL[0][j] : bH[0][j - 2];
            const long bv1 = (j < 2) ? bL[1][j] : bH[1][j - 2];
            #pragma unroll
            for (int mi = 0; mi < 4; ++mi) {
                const long av = (j < 2) ? aL[mi][j] : aH[mi][j - 2];
                ac[mi][0] = __builtin_amdgcn_mfma_f32_16x16x32_fp8_fp8(
                    av, bv0, ac[mi][0], 0, 0, 0);
                ac[mi][1] = __builtin_amdgcn_mfma_f32_16x16x32_fp8_fp8(
                    av, bv1, ac[mi][1], 0, 0, 0);
            }
        }
        __builtin_amdgcn_s_setprio(0);
    };

    float lsum = 0.f;

    // fused loss epilogue for tile j (diag from LDS, no vmem); re-zeros acc
    auto epi = [&](int j) {
        const int rgb = bm * 256;                  // global row base
        const int cgb = bn0 * 256 + j * 256;       // global col base
        auto sumq = [&](f32x4 (&ac)[4][2], int qm, int qn) {
            #pragma unroll
            for (int mi = 0; mi < 4; ++mi) {
                const int rwl = qm * 128 + wm * 64 + mi * 16 + fc * 4;
                const f32x4 dr = *(const f32x4*)&dAr[rwl];
                #pragma unroll
                for (int ni = 0; ni < 2; ++ni) {
                    const int cll = qn * 128 + wn * 32 + ni * 16 + frow;
                    const float dc = dBc[j * 256 + cll];
                    #pragma unroll
                    for (int r = 0; r < 4; ++r) {
                        if (rgb + rwl + r != cgb + cll) {
                            const float sc = ac[mi][ni][r];
                            lsum += fmaxf(0.f, 1.0f - dc + sc)
                                  + fmaxf(0.f, 1.0f - dr[r] + sc);
                        }
                    }
                }
            }
        };
        sumq(acc00, 0, 0); sumq(acc01, 0, 1); sumq(acc11, 1, 1); sumq(acc10, 1, 0);
        #pragma unroll
        for (int mi = 0; mi < 4; ++mi)
            #pragma unroll
            for (int ni = 0; ni < 2; ++ni) {
                acc00[mi][ni] = zero; acc01[mi][ni] = zero;
                acc11[mi][ni] = zero; acc10[mi][ni] = zero;
            }
    };

    #define BAR __builtin_amdgcn_s_barrier()
    #define LGKM0_FENCE do { \
        asm volatile("s_waitcnt lgkmcnt(0)" ::: "memory"); \
        __builtin_amdgcn_sched_barrier(0); } while (0)

    l64x2 aL[4], aH[4];     // current A-half frags (A0 in p1-p2, A1 in p3-p4)
    l64x2 b0L[2], b0H[2];   // B-half0, held p1 -> p4
    l64x2 bBL[2], bBH[2];   // B-half1

    // ---- prologue: diag -> LDS (own vmcnt, drained by compiler before the
    // ds_write; fenced so staging can't interleave), then stage window 0 ----
    if (tid < 256) dAr[tid] = diag[bm * 256 + tid];
    {
        const float2 v = *(const float2*)&diag[(blockIdx.x & 7) * 1024 + tid * 2];
        dBc[tid * 2] = v.x; dBc[tid * 2 + 1] = v.y;
    }
    __builtin_amdgcn_sched_barrier(0);
    stageA(0, 0, 0); stageB(0, 0, 0); stageB(0, 1, 0); stageA(0, 1, 0);
    asm volatile("s_waitcnt vmcnt(2)" ::: "memory");
    BAR;

    // ---- main pipeline: windows g=0..14 stage window g+1 into buf^1 ----
    #pragma unroll 1
    for (int g = 0; g < 15; ++g) {
        const int b = g & 1, nb = b ^ 1;

        // P1: quadrant (0,0) — 12 ds_reads, stage A0(g+1)
        ldA(aL, aH, b, 0);
        ldB(b0L, b0H, b, 0);
        stageA(nb, 0, g + 1);
        asm volatile("s_waitcnt vmcnt(4) lgkmcnt(8)" ::: "memory");  // drains B1(g)
        BAR;
        LGKM0_FENCE;
        mmaq(acc00, aL, aH, b0L, b0H);

        // P2: quadrant (0,1) — 4 ds_reads, stage B0(g+1)
        ldB(bBL, bBH, b, 1);
        stageB(nb, 0, g + 1);
        asm volatile("s_waitcnt vmcnt(4)" ::: "memory");             // drains A1(g)
        BAR;
        LGKM0_FENCE;
        mmaq(acc01, aL, aH, bBL, bBH);

        // P3: quadrant (1,1) — 8 ds_reads, stage B1(g+1)
        ldA(aL, aH, b, 1);
        stageB(nb, 1, g + 1);
        asm volatile("s_waitcnt vmcnt(4)" ::: "memory");             // drains A0(g+1)
        BAR;
        LGKM0_FENCE;
        mmaq(acc11, aL, aH, bBL, bBH);

        // P4: quadrant (1,0) — 0 ds_reads (B0 held), stage A1(g+1)
        stageA(nb, 1, g + 1);
        asm volatile("s_waitcnt vmcnt(4)" ::: "memory");             // drains B0(g+1)
        BAR;
        __builtin_amdgcn_sched_barrier(0);
        mmaq(acc10, aL, aH, b0L, b0H);

        if ((g & 3) == 3) epi(g >> 2);   // tiles 0,1,2: overlap next staging
    }

    // ---- tail: window 15 in buf 1, no staging; drain 2 -> 0 ----
    {
        ldA(aL, aH, 1, 0);
        ldB(b0L, b0H, 1, 0);
        asm volatile("s_waitcnt vmcnt(2)" ::: "memory");             // drains B1(15)
        BAR;
        LGKM0_FENCE;
        mmaq(acc00, aL, aH, b0L, b0H);

        ldB(bBL, bBH, 1, 1);
        asm volatile("s_waitcnt vmcnt(0)" ::: "memory");             // drains A1(15)
        BAR;
        LGKM0_FENCE;
        mmaq(acc01, aL, aH, bBL, bBH);

        ldA(aL, aH, 1, 1);
        LGKM0_FENCE;
        mmaq(acc11, aL, aH, bBL, bBH);
        mmaq(acc10, aL, aH, b0L, b0H);
    }
    epi(3);

    // ---- block reduction + single atomic + merged finalize ----
    #pragma unroll
    for (int off = 32; off; off >>= 1) lsum += __shfl_down(lsum, off);
    if (l == 0) part[w] = lsum;
    __syncthreads();
    if (tid == 0) {
        float bs = 0.f;
        #pragma unroll
        for (int i = 0; i < 8; ++i) bs += part[i];
        atomicAdd(acc_out, (double)bs);
        __threadfence();
        unsigned int old = atomicAdd(cnt, 1u);
        if (old == 255u) {   // last of 256 blocks: all adds visible
            double v = atomicAdd(acc_out, 0.0);   // device-scope read
            out[0] = (float)(v * (1.0 / (double)NR));
        }
    }
}

extern "C" void kernel_launch(void* const* d_in, const int* in_sizes, int n_in,
                              void* d_out, int out_size, void* d_ws, size_t ws_size,
                              hipStream_t stream)
{
    const float* im = (const float*)d_in[0];
    const float* s  = (const float*)d_in[1];

    char* ws = (char*)d_ws;
    unsigned char* im_q = (unsigned char*)ws;                                 // 4 MB
    unsigned char* s_q  = (unsigned char*)(ws + (size_t)NR * DIM);            // 4 MB
    float* diag         = (float*)(ws + (size_t)NR * DIM * 2);                // 32 KB
    double* acc         = (double*)(ws + (size_t)NR * DIM * 2 + NR * 4);      // 8 B
    unsigned int* cnt   = (unsigned int*)(ws + (size_t)NR * DIM * 2 + NR * 4 + 8);

    normalize_kernel<<<NR, 256, 0, stream>>>(im, s, im_q, s_q, diag, acc, cnt);

    gemm_loss_kernel<<<256, 512, 0, stream>>>(im_q, s_q, diag, acc, cnt,
                                              (float*)d_out);
}